// Round 25
// baseline (790.496 us; speedup 1.0000x reference)
//
#include <hip/hip_runtime.h>
#include <hip/hip_bf16.h>
#include <math.h>

// Problem constants
#define B_ 2
#define S_ 2048
#define D_ 4096
#define H_ 32
#define G_ 8
#define HD_ 128
#define GROUP_ 4
#define KVSTR_ (2 * G_ * HD_)   // 2048: head-stride of merged KV buffer (16 slots)
#define SCALE_ 0.08838834764831845f

typedef short bfv8 __attribute__((ext_vector_type(8)));   // 8 bf16 (4 VGPRs)
typedef float f32x4 __attribute__((ext_vector_type(4)));

__device__ __forceinline__ f32x4 mfma16(bfv8 a, bfv8 b, f32x4 c) {
  return __builtin_amdgcn_mfma_f32_16x16x32_bf16(a, b, c, 0, 0, 0);
}

__device__ __forceinline__ ushort f2bf_bits(float f) {
  __hip_bfloat16 h = __float2bfloat16(f);
  return *reinterpret_cast<ushort*>(&h);
}

// async global->LDS, 16B per lane; LDS dest = wave-uniform base + lane*16 (HW);
// global src is per-lane (enables source-side swizzle per rule #21).
__device__ __forceinline__ void gload16(const short* g, short* l) {
  __builtin_amdgcn_global_load_lds(
      (const __attribute__((address_space(1))) void*)g,
      (__attribute__((address_space(3))) void*)l, 16, 0, 0);
}

// ---------------- f32 -> bf16 elementwise convert (x) ----------------
__global__ __launch_bounds__(256) void k_cvt(const float* __restrict__ in,
                                             ushort* __restrict__ out, int n4) {
  int i = blockIdx.x * 256 + threadIdx.x;
  if (i >= n4) return;
  float4 v = *(const float4*)(in + (size_t)i * 4);
  ushort4 o;
  o.x = f2bf_bits(v.x); o.y = f2bf_bits(v.y); o.z = f2bf_bits(v.z); o.w = f2bf_bits(v.w);
  *(ushort4*)(out + (size_t)i * 4) = o;
}

// ---------------- transpose (R x C) f32 -> (C x R) bf16, vectorized ----------
__global__ __launch_bounds__(256) void k_transpose(const float* __restrict__ in,
                                                   ushort* __restrict__ out,
                                                   int R, int C) {
  __shared__ ushort tile[32][36];
  int bc = blockIdx.x * 32;
  int br = blockIdx.y * 32;
  int t = threadIdx.x;
  int rr = t >> 3;            // 0..31
  int c4 = (t & 7) * 4;       // 0,4,..,28
  float4 v = *(const float4*)(in + (size_t)(br + rr) * C + bc + c4);
  tile[rr][c4 + 0] = f2bf_bits(v.x);
  tile[rr][c4 + 1] = f2bf_bits(v.y);
  tile[rr][c4 + 2] = f2bf_bits(v.z);
  tile[rr][c4 + 3] = f2bf_bits(v.w);
  __syncthreads();
  int cc = t >> 3;            // 0..31
  int r4 = (t & 7) * 4;       // 0,4,..,28
  ushort4 o;
  o.x = tile[r4 + 0][cc];
  o.y = tile[r4 + 1][cc];
  o.z = tile[r4 + 2][cc];
  o.w = tile[r4 + 3][cc];
  *(ushort4*)(out + (size_t)(bc + cc) * R + br + r4) = o;
}

// V-half of KV (B,S,16,HD) bf16 -> VT (B,G,HD,S) bf16
__global__ __launch_bounds__(256) void k_transpose_v(const ushort* __restrict__ v,
                                                     ushort* __restrict__ vt,
                                                     int hstride, int hoff) {
  __shared__ ushort tile[32][33];
  int bg = blockIdx.z;
  int b = bg / G_, g = bg % G_;
  int s0 = blockIdx.y * 32;
  int h0 = blockIdx.x * 32;
  int tx = threadIdx.x, ty = threadIdx.y;
  const ushort* src = v + (size_t)b * S_ * hstride + (size_t)(hoff + g) * HD_;
  ushort* dst = vt + (size_t)(b * G_ + g) * HD_ * S_;
  for (int ii = 0; ii < 4; ii++) {
    int i = ty + ii * 8;
    tile[i][tx] = src[(size_t)(s0 + i) * hstride + h0 + tx];
  }
  __syncthreads();
  for (int ii = 0; ii < 4; ii++) {
    int i = ty + ii * 8;
    dst[(size_t)(h0 + i) * S_ + s0 + tx] = tile[tx][i];
  }
}

// ---------------- RoPE (in-place, bf16 t; f32 cos/sin), 4 items/block --------
__global__ __launch_bounds__(256) void k_rope(__hip_bfloat16* __restrict__ t,
                                              const float* __restrict__ cosb,
                                              const float* __restrict__ sinb,
                                              int hstride, int nlaunch, float scale) {
  int item = blockIdx.x * 4 + (threadIdx.x >> 6);
  int head = item % nlaunch;
  int row = item / nlaunch;      // b*S + s
  int s = row & (S_ - 1);
  int l = threadIdx.x & 63;
  size_t base = (size_t)row * hstride * HD_ + (size_t)head * HD_;
  float x1 = __bfloat162float(t[base + l]);
  float x2 = __bfloat162float(t[base + 64 + l]);
  float c1 = cosb[s * HD_ + l];
  float sn1 = sinb[s * HD_ + l];
  float c2 = cosb[s * HD_ + 64 + l];
  float sn2 = sinb[s * HD_ + 64 + l];
  t[base + l] = __float2bfloat16((x1 * c1 - x2 * sn1) * scale);
  t[base + 64 + l] = __float2bfloat16((x2 * c2 + x1 * sn2) * scale);
}

// ---------------- GEMM 128^2 (m97 structure) for merged KV projection --------
template <typename OT>
__global__ __launch_bounds__(256) void k_gemm_bt(const __hip_bfloat16* __restrict__ Ab,
                                                 const __hip_bfloat16* __restrict__ BTb,
                                                 OT* __restrict__ Cb,
                                                 int M, int N, int K) {
  __shared__ short sA[128 * 32];
  __shared__ short sB[128 * 32];
  int t = threadIdx.x;
  int w = t >> 6;
  int l = t & 63;
  int row0 = blockIdx.y * 128;
  int col0 = blockIdx.x * 128;
  int wr = (w >> 1) * 64;
  int wc = (w & 1) * 64;
  int fr = l & 15;
  int fq = l >> 4;
  int fo = fq * 8;
  int srow = l >> 2;
  int schk = (l & 3) * 8;

  const short* gA = (const short*)Ab;
  const short* gB = (const short*)BTb;

  f32x4 acc[4][4];
#pragma unroll
  for (int m = 0; m < 4; m++)
#pragma unroll
    for (int n = 0; n < 4; n++) acc[m][n] = (f32x4){0.f, 0.f, 0.f, 0.f};

  for (int k0 = 0; k0 < K; k0 += 32) {
    __syncthreads();
#pragma unroll
    for (int j = 0; j < 2; j++) {
      int r = w * 32 + j * 16;
      gload16(gA + (size_t)(row0 + r + srow) * K + k0 + schk, &sA[r * 32]);
      gload16(gB + (size_t)(col0 + r + srow) * K + k0 + schk, &sB[r * 32]);
    }
    __syncthreads();
    bfv8 af[4], bff[4];
#pragma unroll
    for (int m = 0; m < 4; m++) af[m] = *(const bfv8*)(sA + (wr + m * 16 + fr) * 32 + fo);
#pragma unroll
    for (int n = 0; n < 4; n++) bff[n] = *(const bfv8*)(sB + (wc + n * 16 + fr) * 32 + fo);
#pragma unroll
    for (int m = 0; m < 4; m++)
#pragma unroll
      for (int n = 0; n < 4; n++)
        acc[m][n] = mfma16(af[m], bff[n], acc[m][n]);
  }
#pragma unroll
  for (int m = 0; m < 4; m++)
#pragma unroll
    for (int n = 0; n < 4; n++)
#pragma unroll
      for (int j = 0; j < 4; j++) {
        int r = row0 + wr + m * 16 + fq * 4 + j;
        int c = col0 + wc + n * 16 + fr;
        if constexpr (__is_same(OT, float)) {
          Cb[(size_t)r * N + c] = acc[m][n][j];
        } else {
          Cb[(size_t)r * N + c] = __float2bfloat16(acc[m][n][j]);
        }
      }
}

// ---------------- GEMM 256^2, BK=64, 8 waves, 4-phase counted-vmcnt ----------
// (r22-best configuration: dim3(16,16) grid, setprio around MFMA clusters)
template <typename OT>
__global__ __launch_bounds__(512, 2) void k_gemm256(const __hip_bfloat16* __restrict__ Ab,
                                                    const __hip_bfloat16* __restrict__ BTb,
                                                    OT* __restrict__ Cb,
                                                    int M, int N, int K) {
  __shared__ short sA[2][2][8192];
  __shared__ short sB[2][2][8192];
  int tid = threadIdx.x;
  int wid = tid >> 6;
  int l = tid & 63;
  int wr = (wid >> 2) * 128;
  int wc = (wid & 3) * 64;
  int fr = l & 15, fq = l >> 4;
  int cswz = (fq ^ ((fr >> 1) & 3)) * 8;
  int row0 = blockIdx.y * 256, col0 = blockIdx.x * 256;
  int sr = l >> 2;
  int schunk = ((l & 3) ^ (((wid * 16 + sr) >> 1) & 3)) * 8;
  const short* gA = (const short*)Ab;
  const short* gB = (const short*)BTb;

  f32x4 acc[8][4];
#pragma unroll
  for (int m = 0; m < 8; m++)
#pragma unroll
    for (int n = 0; n < 4; n++) acc[m][n] = (f32x4){0.f, 0.f, 0.f, 0.f};

#define STAGE256(buf, kh, isB, kt)                                                   \
  {                                                                                  \
    const short* g_ = (isB) ? gB : gA;                                               \
    int b0_ = (isB) ? col0 : row0;                                                   \
    short* s_ = (isB) ? &sB[buf][kh][0] : &sA[buf][kh][0];                           \
    int k0_ = (kt) * 64 + (kh) * 32;                                                 \
    _Pragma("unroll")                                                                \
    for (int i_ = 0; i_ < 2; i_++) {                                                 \
      int r_ = i_ * 128 + wid * 16 + sr;                                             \
      gload16(g_ + (size_t)(b0_ + r_) * K + k0_ + schunk,                            \
              s_ + (i_ * 128 + wid * 16) * 32);                                      \
    }                                                                                \
  }

  bfv8 bf[4];
#define COMPUTE256(cur, kh, mg, loadB)                                               \
  {                                                                                  \
    if (loadB) {                                                                     \
      _Pragma("unroll")                                                              \
      for (int n_ = 0; n_ < 4; n_++)                                                 \
        bf[n_] = *(const bfv8*)&sB[cur][kh][(wc + n_ * 16 + fr) * 32 + cswz];        \
    }                                                                                \
    bfv8 af_[4];                                                                     \
    _Pragma("unroll")                                                                \
    for (int j_ = 0; j_ < 4; j_++)                                                   \
      af_[j_] = *(const bfv8*)&sA[cur][kh][(wr + ((mg) * 4 + j_) * 16 + fr) * 32 + cswz]; \
    __builtin_amdgcn_s_setprio(1);                                                   \
    _Pragma("unroll")                                                                \
    for (int j_ = 0; j_ < 4; j_++)                                                   \
      _Pragma("unroll")                                                              \
      for (int n_ = 0; n_ < 4; n_++)                                                 \
        acc[(mg) * 4 + j_][n_] = mfma16(af_[j_], bf[n_], acc[(mg) * 4 + j_][n_]);    \
    __builtin_amdgcn_s_setprio(0);                                                   \
  }

  int NT = K / 64;
  STAGE256(0, 0, false, 0);
  STAGE256(0, 0, true, 0);
  STAGE256(0, 1, false, 0);
  STAGE256(0, 1, true, 0);

  for (int t = 0; t < NT - 1; t++) {
    int cur = t & 1, nxt = cur ^ 1;
    asm volatile("s_waitcnt vmcnt(4)" ::: "memory");
    __builtin_amdgcn_s_barrier();
    STAGE256(nxt, 0, false, t + 1);
    COMPUTE256(cur, 0, 0, true);
    STAGE256(nxt, 0, true, t + 1);
    COMPUTE256(cur, 0, 1, false);
    asm volatile("s_waitcnt vmcnt(4)" ::: "memory");
    __builtin_amdgcn_s_barrier();
    STAGE256(nxt, 1, false, t + 1);
    COMPUTE256(cur, 1, 0, true);
    STAGE256(nxt, 1, true, t + 1);
    COMPUTE256(cur, 1, 1, false);
  }
  {
    int cur = (NT - 1) & 1;
    asm volatile("s_waitcnt vmcnt(4)" ::: "memory");
    __builtin_amdgcn_s_barrier();
    COMPUTE256(cur, 0, 0, true);
    COMPUTE256(cur, 0, 1, false);
    asm volatile("s_waitcnt vmcnt(0)" ::: "memory");
    __builtin_amdgcn_s_barrier();
    COMPUTE256(cur, 1, 0, true);
    COMPUTE256(cur, 1, 1, false);
  }
#undef STAGE256
#undef COMPUTE256

#pragma unroll
  for (int m = 0; m < 8; m++)
#pragma unroll
    for (int n = 0; n < 4; n++)
#pragma unroll
      for (int j = 0; j < 4; j++) {
        int r = row0 + wr + m * 16 + fq * 4 + j;
        int c = col0 + wc + n * 16 + fr;
        if constexpr (__is_same(OT, float)) {
          Cb[(size_t)r * N + c] = acc[m][n][j];
        } else {
          Cb[(size_t)r * N + c] = __float2bfloat16(acc[m][n][j]);
        }
      }
}

// ---------------- flash attention v5f: v5e with 40KB LDS (4 blocks/CU) -------
// sP stride 68 -> 32 (two-pass PV, r10-v3-verified structure): LDS = 16K sK
// + 16K sV + 8K sP = 40960 B exactly -> 4 blocks/CU (was 3) and the whole
// 1024-block grid co-resident (no dispatch tail).
//  A: vmcnt(2)+bar  -> K landed; QK^T+softmax while V streams in
//  B: vmcnt(0)+bar  -> V landed & all waves past QK^T; issue K(t+1); PV x2
//  C: bar           -> all waves past PV; issue V(t+1)
#define PSTR 32
__global__ __launch_bounds__(512) void k_attn5(const __hip_bfloat16* __restrict__ Qb,
                                               const __hip_bfloat16* __restrict__ KVb,
                                               const __hip_bfloat16* __restrict__ VTb,
                                               __hip_bfloat16* __restrict__ ctx) {
  __shared__ short sK[64 * 128];        // [k][d], rows 256B, 16 chunks
  __shared__ short sV[128 * 64];        // [d][k], rows 128B, 8 chunks
  __shared__ short sP[8][16 * PSTR];    // per-wave P[16 q][32 k] (two passes)

  const int nQB = S_ / 128;             // 16
  int blk = blockIdx.x;
  int qb = (nQB - 1) - (blk % nQB);     // heavy blocks dispatched first
  int bh = blk / nQB;
  int h = bh % H_;
  int b = bh / H_;
  int g = h / GROUP_;
  int q0 = qb * 128;

  int t = threadIdx.x;
  int wid = t >> 6;
  int l = t & 63;
  int fr = l & 15, fq = l >> 4, fo = fq * 8;
  int wq0 = q0 + wid * 16;              // this wave's q rows

  const short* qp = (const short*)Qb + (size_t)b * S_ * H_ * HD_ + (size_t)h * HD_;
  const short* kp = (const short*)KVb + (size_t)b * S_ * KVSTR_ + (size_t)g * HD_;
  const short* vp = (const short*)VTb + (size_t)(b * G_ + g) * HD_ * S_;

  bfv8 qf[4];
#pragma unroll
  for (int c = 0; c < 4; c++)
    qf[c] = *(const bfv8*)(qp + (size_t)(wq0 + fr) * (H_ * HD_) + c * 32 + fo);

  f32x4 acc[8];
#pragma unroll
  for (int n = 0; n < 8; n++) acc[n] = (f32x4){0.f, 0.f, 0.f, 0.f};
  float m[4], ls[4];
#pragma unroll
  for (int j = 0; j < 4; j++) { m[j] = -INFINITY; ls[j] = 0.f; }

  // staging lane decomposition
  int krow_i = l >> 4;   // K: 4 rows per issue
  int kchk = l & 15;     // K chunk 0..15
  int vrow_i = l >> 3;   // V: 8 rows per issue
  int vchk = l & 7;      // V chunk 0..7

#define STAGE_K(k0s)                                                                 \
  _Pragma("unroll")                                                                  \
  for (int j = 0; j < 2; j++) {                                                      \
    int base = wid * 8 + j * 4;                                                      \
    int r = base + krow_i;                                                           \
    gload16(kp + (size_t)((k0s) + r) * KVSTR_ + ((kchk ^ (r & 7)) * 8),              \
            &sK[base * 128]);                                                        \
  }
#define STAGE_V(k0s)                                                                 \
  _Pragma("unroll")                                                                  \
  for (int j = 0; j < 2; j++) {                                                      \
    int base = wid * 16 + j * 8;                                                     \
    int r = base + vrow_i;                                                           \
    gload16(vp + (size_t)r * S_ + (k0s) + ((vchk ^ (r & 7)) * 8), &sV[base * 64]);   \
  }

  int nkt = 2 * qb + 2;  // 64-k tiles covering k <= q0+127
  // prologue: stage tile 0 (K first, then V — vmcnt is oldest-first)
  STAGE_K(0);
  STAGE_V(0);

  for (int kt = 0; kt < nkt; kt++) {
    int k0 = kt * 64;
    // ---- A: K landed (V's 2 loads may still be in flight)
    asm volatile("s_waitcnt vmcnt(2)" ::: "memory");
    __builtin_amdgcn_s_barrier();

    // ---- QK^T over 64 k (4 sub-tiles of 16)
    f32x4 sf[4];
#pragma unroll
    for (int ks = 0; ks < 4; ks++) {
      sf[ks] = (f32x4){0.f, 0.f, 0.f, 0.f};
      int row = ks * 16 + fr;
      int rx = row & 7;
#pragma unroll
      for (int c = 0; c < 4; c++) {
        bfv8 kf = *(const bfv8*)&sK[row * 128 + (((c * 4 + fq) ^ rx) * 8)];
        sf[ks] = mfma16(qf[c], kf, sf[ks]);
      }
    }

    // ---- causal mask + online softmax (rows = fq*4+j, cols = ks*16+fr)
    float p[4][4], red[4];
#pragma unroll
    for (int j = 0; j < 4; j++) {
      int q = wq0 + fq * 4 + j;
#pragma unroll
      for (int ks = 0; ks < 4; ks++)
        if (k0 + ks * 16 + fr > q) sf[ks][j] = -INFINITY;
      red[j] = fmaxf(fmaxf(sf[0][j], sf[1][j]), fmaxf(sf[2][j], sf[3][j]));
    }
#pragma unroll
    for (int off = 1; off < 16; off <<= 1)
#pragma unroll
      for (int j = 0; j < 4; j++)
        red[j] = fmaxf(red[j], __shfl_xor(red[j], off, 64));

    // wave-uniform: does any row's max grow this tile? (if not, sc==1 for all)
    bool grow = !__all((red[0] <= m[0]) & (red[1] <= m[1]) &
                       (red[2] <= m[2]) & (red[3] <= m[3]));
    if (grow) {
#pragma unroll
      for (int j = 0; j < 4; j++) {
        float nm = fmaxf(m[j], red[j]);
        float scj = __expf(m[j] - nm);   // row-uniform across the 16 fr-lanes
        m[j] = nm;
        ls[j] *= scj;
#pragma unroll
        for (int n = 0; n < 8; n++) acc[n][j] *= scj;
      }
    }
#pragma unroll
    for (int j = 0; j < 4; j++) {
#pragma unroll
      for (int ks = 0; ks < 4; ks++) p[ks][j] = __expf(sf[ks][j] - m[j]);
      // deferred denominator: per-lane partial (16-lane reduce after the loop)
      ls[j] += (p[0][j] + p[1][j]) + (p[2][j] + p[3][j]);
    }

    // ---- B: V landed; all waves past QK^T (barrier orders sK overwrite)
    asm volatile("s_waitcnt vmcnt(0)" ::: "memory");
    __builtin_amdgcn_s_barrier();
    if (kt + 1 < nkt) STAGE_K(k0 + 64);   // overlaps with PV below

    // ---- PV in two 32-k passes through halved sP (own-wave; in-wave DS order)
#pragma unroll
    for (int hp = 0; hp < 2; hp++) {
#pragma unroll
      for (int j = 0; j < 4; j++)
#pragma unroll
        for (int k2 = 0; k2 < 2; k2++)
          sP[wid][(fq * 4 + j) * PSTR + k2 * 16 + fr] = f2bf_bits(p[hp * 2 + k2][j]);
      bfv8 pa = *(const bfv8*)&sP[wid][fr * PSTR + fo];
#pragma unroll
      for (int n = 0; n < 8; n++) {
        int row = n * 16 + fr;
        int rx = row & 7;
        bfv8 vf = *(const bfv8*)&sV[row * 64 + (((hp * 4 + fq) ^ rx) * 8)];
        acc[n] = mfma16(pa, vf, acc[n]);
      }
    }

    // ---- C: all waves past PV -> safe to overwrite sV; overlaps next QK^T
    if (kt + 1 < nkt) {
      __builtin_amdgcn_s_barrier();
      STAGE_V(k0 + 64);
    }
  }
#undef STAGE_K
#undef STAGE_V

  // final 16-lane reduce of the deferred denominator (once, not per tile)
#pragma unroll
  for (int off = 1; off < 16; off <<= 1)
#pragma unroll
    for (int j = 0; j < 4; j++)
      ls[j] += __shfl_xor(ls[j], off, 64);
  float inv[4];
#pragma unroll
  for (int j = 0; j < 4; j++) inv[j] = 1.0f / ls[j];

#pragma unroll
  for (int n = 0; n < 8; n++)
#pragma unroll
    for (int j = 0; j < 4; j++) {
      int q = wq0 + fq * 4 + j;
      float o = acc[n][j] * inv[j];
      ctx[(size_t)(b * S_ + q) * (H_ * HD_) + h * HD_ + n * 16 + fr] = __float2bfloat16(o);
    }
}

extern "C" void kernel_launch(void* const* d_in, const int* in_sizes, int n_in,
                              void* d_out, int out_size, void* d_ws, size_t ws_size,
                              hipStream_t stream) {
  (void)in_sizes; (void)n_in; (void)out_size; (void)ws_size;
  const float* x    = (const float*)d_in[0];
  const float* Wq   = (const float*)d_in[1];
  const float* Wk   = (const float*)d_in[2];
  const float* Wv   = (const float*)d_in[3];
  const float* Wo   = (const float*)d_in[4];
  const float* cosb = (const float*)d_in[5];
  const float* sinb = (const float*)d_in[6];
  // d_in[7] = mask (fixed causal triu), d_in[8] = start_pos (0) — implemented directly.

  char* ws = (char*)d_ws;
  __hip_bfloat16* xb  = (__hip_bfloat16*)(ws + 0);           // (B,S,D) bf16, later Cx
  __hip_bfloat16* WqT = (__hip_bfloat16*)(ws + 33554432);    // 4096x4096, later WoT
  __hip_bfloat16* WkT = (__hip_bfloat16*)(ws + 67108864);    // 1024x4096 \ contiguous:
  __hip_bfloat16* WvT = (__hip_bfloat16*)(ws + 75497472);    // 1024x4096 / WkvT (2048x4096)
  __hip_bfloat16* Qb  = (__hip_bfloat16*)(ws + 83886080);    // (B,S,H,HD)
  __hip_bfloat16* KVb = (__hip_bfloat16*)(ws + 117440512);   // (B,S,16,HD): K slots 0-7, V slots 8-15
  __hip_bfloat16* VTb = (__hip_bfloat16*)(ws + 134217728);   // (B,G,HD,S)
  __hip_bfloat16* Cx  = xb;                                  // alias

  k_cvt<<<(B_ * S_ * D_ / 4 + 255) / 256, 256, 0, stream>>>(x, (ushort*)xb, B_ * S_ * D_ / 4);
  k_transpose<<<dim3(128, 128), 256, 0, stream>>>(Wq, (ushort*)WqT, 4096, 4096);
  k_transpose<<<dim3(32, 128), 256, 0, stream>>>(Wk, (ushort*)WkT, 4096, 1024);
  k_transpose<<<dim3(32, 128), 256, 0, stream>>>(Wv, (ushort*)WvT, 4096, 1024);

  // projections: Q on the 256^2 counted-vmcnt kernel; K+V merged on 128^2 (N=2048)
  k_gemm256<__hip_bfloat16><<<dim3(16, 16), 512, 0, stream>>>(xb, WqT, Qb, 4096, 4096, 4096);
  k_gemm_bt<__hip_bfloat16><<<dim3(16, 32), 256, 0, stream>>>(xb, WkT, KVb, 4096, 2048, 4096);

  // WqT region is free now — put WoT there
  k_transpose<<<dim3(128, 128), 256, 0, stream>>>(Wo, (ushort*)WqT, 4096, 4096);

  // RoPE: Q (stride 32 heads, launch 32) and K-half of KV (stride 16, launch 8)
  k_rope<<<4096 * 32 / 4, 256, 0, stream>>>(Qb, cosb, sinb, 32, 32, SCALE_);
  k_rope<<<4096 * 8 / 4, 256, 0, stream>>>((__hip_bfloat16*)KVb, cosb, sinb, 16, 8, 1.0f);

  // V-half of KV -> VT
  k_transpose_v<<<dim3(4, 64, 16), dim3(32, 8), 0, stream>>>((const ushort*)KVb, (ushort*)VTb,
                                                             KVSTR_, G_);

  k_attn5<<<B_ * H_ * (S_ / 128), 512, 0, stream>>>(Qb, KVb, VTb, Cx);

  // output projection (f32 into d_out) on the 256^2 kernel
  k_gemm256<float><<<dim3(16, 16), 512, 0, stream>>>(Cx, WqT, (float*)d_out, 4096, 4096, 4096);
}

// Round 26
// 683.042 us; speedup vs baseline: 1.1573x; 1.1573x over previous
//
#include <hip/hip_runtime.h>
#include <hip/hip_bf16.h>
#include <math.h>

// Problem constants
#define B_ 2
#define S_ 2048
#define D_ 4096
#define H_ 32
#define G_ 8
#define HD_ 128
#define GROUP_ 4
#define KVSTR_ (2 * G_ * HD_)   // 2048: head-stride of merged KV buffer (16 slots)
#define SCALE_ 0.08838834764831845f

typedef short bfv8 __attribute__((ext_vector_type(8)));   // 8 bf16 (4 VGPRs)
typedef float f32x4 __attribute__((ext_vector_type(4)));

__device__ __forceinline__ f32x4 mfma16(bfv8 a, bfv8 b, f32x4 c) {
  return __builtin_amdgcn_mfma_f32_16x16x32_bf16(a, b, c, 0, 0, 0);
}

__device__ __forceinline__ ushort f2bf_bits(float f) {
  __hip_bfloat16 h = __float2bfloat16(f);
  return *reinterpret_cast<ushort*>(&h);
}

// async global->LDS, 16B per lane; LDS dest = wave-uniform base + lane*16 (HW);
// global src is per-lane (enables source-side swizzle per rule #21).
__device__ __forceinline__ void gload16(const short* g, short* l) {
  __builtin_amdgcn_global_load_lds(
      (const __attribute__((address_space(1))) void*)g,
      (__attribute__((address_space(3))) void*)l, 16, 0, 0);
}

// ---------------- f32 -> bf16 elementwise convert (x) ----------------
__global__ __launch_bounds__(256) void k_cvt(const float* __restrict__ in,
                                             ushort* __restrict__ out, int n4) {
  int i = blockIdx.x * 256 + threadIdx.x;
  if (i >= n4) return;
  float4 v = *(const float4*)(in + (size_t)i * 4);
  ushort4 o;
  o.x = f2bf_bits(v.x); o.y = f2bf_bits(v.y); o.z = f2bf_bits(v.z); o.w = f2bf_bits(v.w);
  *(ushort4*)(out + (size_t)i * 4) = o;
}

// ---------------- transpose (R x C) f32 -> (C x R) bf16, vectorized ----------
__global__ __launch_bounds__(256) void k_transpose(const float* __restrict__ in,
                                                   ushort* __restrict__ out,
                                                   int R, int C) {
  __shared__ ushort tile[32][36];
  int bc = blockIdx.x * 32;
  int br = blockIdx.y * 32;
  int t = threadIdx.x;
  int rr = t >> 3;            // 0..31
  int c4 = (t & 7) * 4;       // 0,4,..,28
  float4 v = *(const float4*)(in + (size_t)(br + rr) * C + bc + c4);
  tile[rr][c4 + 0] = f2bf_bits(v.x);
  tile[rr][c4 + 1] = f2bf_bits(v.y);
  tile[rr][c4 + 2] = f2bf_bits(v.z);
  tile[rr][c4 + 3] = f2bf_bits(v.w);
  __syncthreads();
  int cc = t >> 3;            // 0..31
  int r4 = (t & 7) * 4;       // 0,4,..,28
  ushort4 o;
  o.x = tile[r4 + 0][cc];
  o.y = tile[r4 + 1][cc];
  o.z = tile[r4 + 2][cc];
  o.w = tile[r4 + 3][cc];
  *(ushort4*)(out + (size_t)(bc + cc) * R + br + r4) = o;
}

// V-half of KV (B,S,16,HD) bf16 -> VT (B,G,HD,S) bf16
__global__ __launch_bounds__(256) void k_transpose_v(const ushort* __restrict__ v,
                                                     ushort* __restrict__ vt,
                                                     int hstride, int hoff) {
  __shared__ ushort tile[32][33];
  int bg = blockIdx.z;
  int b = bg / G_, g = bg % G_;
  int s0 = blockIdx.y * 32;
  int h0 = blockIdx.x * 32;
  int tx = threadIdx.x, ty = threadIdx.y;
  const ushort* src = v + (size_t)b * S_ * hstride + (size_t)(hoff + g) * HD_;
  ushort* dst = vt + (size_t)(b * G_ + g) * HD_ * S_;
  for (int ii = 0; ii < 4; ii++) {
    int i = ty + ii * 8;
    tile[i][tx] = src[(size_t)(s0 + i) * hstride + h0 + tx];
  }
  __syncthreads();
  for (int ii = 0; ii < 4; ii++) {
    int i = ty + ii * 8;
    dst[(size_t)(h0 + i) * S_ + s0 + tx] = tile[tx][i];
  }
}

// ---------------- RoPE (in-place, bf16 t; f32 cos/sin), 4 items/block --------
__global__ __launch_bounds__(256) void k_rope(__hip_bfloat16* __restrict__ t,
                                              const float* __restrict__ cosb,
                                              const float* __restrict__ sinb,
                                              int hstride, int nlaunch, float scale) {
  int item = blockIdx.x * 4 + (threadIdx.x >> 6);
  int head = item % nlaunch;
  int row = item / nlaunch;      // b*S + s
  int s = row & (S_ - 1);
  int l = threadIdx.x & 63;
  size_t base = (size_t)row * hstride * HD_ + (size_t)head * HD_;
  float x1 = __bfloat162float(t[base + l]);
  float x2 = __bfloat162float(t[base + 64 + l]);
  float c1 = cosb[s * HD_ + l];
  float sn1 = sinb[s * HD_ + l];
  float c2 = cosb[s * HD_ + 64 + l];
  float sn2 = sinb[s * HD_ + 64 + l];
  t[base + l] = __float2bfloat16((x1 * c1 - x2 * sn1) * scale);
  t[base + 64 + l] = __float2bfloat16((x2 * c2 + x1 * sn2) * scale);
}

// ---------------- GEMM 128^2 (m97 structure) for merged KV projection --------
template <typename OT>
__global__ __launch_bounds__(256) void k_gemm_bt(const __hip_bfloat16* __restrict__ Ab,
                                                 const __hip_bfloat16* __restrict__ BTb,
                                                 OT* __restrict__ Cb,
                                                 int M, int N, int K) {
  __shared__ short sA[128 * 32];
  __shared__ short sB[128 * 32];
  int t = threadIdx.x;
  int w = t >> 6;
  int l = t & 63;
  int row0 = blockIdx.y * 128;
  int col0 = blockIdx.x * 128;
  int wr = (w >> 1) * 64;
  int wc = (w & 1) * 64;
  int fr = l & 15;
  int fq = l >> 4;
  int fo = fq * 8;
  int srow = l >> 2;
  int schk = (l & 3) * 8;

  const short* gA = (const short*)Ab;
  const short* gB = (const short*)BTb;

  f32x4 acc[4][4];
#pragma unroll
  for (int m = 0; m < 4; m++)
#pragma unroll
    for (int n = 0; n < 4; n++) acc[m][n] = (f32x4){0.f, 0.f, 0.f, 0.f};

  for (int k0 = 0; k0 < K; k0 += 32) {
    __syncthreads();
#pragma unroll
    for (int j = 0; j < 2; j++) {
      int r = w * 32 + j * 16;
      gload16(gA + (size_t)(row0 + r + srow) * K + k0 + schk, &sA[r * 32]);
      gload16(gB + (size_t)(col0 + r + srow) * K + k0 + schk, &sB[r * 32]);
    }
    __syncthreads();
    bfv8 af[4], bff[4];
#pragma unroll
    for (int m = 0; m < 4; m++) af[m] = *(const bfv8*)(sA + (wr + m * 16 + fr) * 32 + fo);
#pragma unroll
    for (int n = 0; n < 4; n++) bff[n] = *(const bfv8*)(sB + (wc + n * 16 + fr) * 32 + fo);
#pragma unroll
    for (int m = 0; m < 4; m++)
#pragma unroll
      for (int n = 0; n < 4; n++)
        acc[m][n] = mfma16(af[m], bff[n], acc[m][n]);
  }
#pragma unroll
  for (int m = 0; m < 4; m++)
#pragma unroll
    for (int n = 0; n < 4; n++)
#pragma unroll
      for (int j = 0; j < 4; j++) {
        int r = row0 + wr + m * 16 + fq * 4 + j;
        int c = col0 + wc + n * 16 + fr;
        if constexpr (__is_same(OT, float)) {
          Cb[(size_t)r * N + c] = acc[m][n][j];
        } else {
          Cb[(size_t)r * N + c] = __float2bfloat16(acc[m][n][j]);
        }
      }
}

// ---------------- GEMM 256^2, BK=64, 8 waves, 4-phase counted-vmcnt ----------
// (r22-best configuration: dim3(16,16) grid, setprio around MFMA clusters)
template <typename OT>
__global__ __launch_bounds__(512, 2) void k_gemm256(const __hip_bfloat16* __restrict__ Ab,
                                                    const __hip_bfloat16* __restrict__ BTb,
                                                    OT* __restrict__ Cb,
                                                    int M, int N, int K) {
  __shared__ short sA[2][2][8192];
  __shared__ short sB[2][2][8192];
  int tid = threadIdx.x;
  int wid = tid >> 6;
  int l = tid & 63;
  int wr = (wid >> 2) * 128;
  int wc = (wid & 3) * 64;
  int fr = l & 15, fq = l >> 4;
  int cswz = (fq ^ ((fr >> 1) & 3)) * 8;
  int row0 = blockIdx.y * 256, col0 = blockIdx.x * 256;
  int sr = l >> 2;
  int schunk = ((l & 3) ^ (((wid * 16 + sr) >> 1) & 3)) * 8;
  const short* gA = (const short*)Ab;
  const short* gB = (const short*)BTb;

  f32x4 acc[8][4];
#pragma unroll
  for (int m = 0; m < 8; m++)
#pragma unroll
    for (int n = 0; n < 4; n++) acc[m][n] = (f32x4){0.f, 0.f, 0.f, 0.f};

#define STAGE256(buf, kh, isB, kt)                                                   \
  {                                                                                  \
    const short* g_ = (isB) ? gB : gA;                                               \
    int b0_ = (isB) ? col0 : row0;                                                   \
    short* s_ = (isB) ? &sB[buf][kh][0] : &sA[buf][kh][0];                           \
    int k0_ = (kt) * 64 + (kh) * 32;                                                 \
    _Pragma("unroll")                                                                \
    for (int i_ = 0; i_ < 2; i_++) {                                                 \
      int r_ = i_ * 128 + wid * 16 + sr;                                             \
      gload16(g_ + (size_t)(b0_ + r_) * K + k0_ + schunk,                            \
              s_ + (i_ * 128 + wid * 16) * 32);                                      \
    }                                                                                \
  }

  bfv8 bf[4];
#define COMPUTE256(cur, kh, mg, loadB)                                               \
  {                                                                                  \
    if (loadB) {                                                                     \
      _Pragma("unroll")                                                              \
      for (int n_ = 0; n_ < 4; n_++)                                                 \
        bf[n_] = *(const bfv8*)&sB[cur][kh][(wc + n_ * 16 + fr) * 32 + cswz];        \
    }                                                                                \
    bfv8 af_[4];                                                                     \
    _Pragma("unroll")                                                                \
    for (int j_ = 0; j_ < 4; j_++)                                                   \
      af_[j_] = *(const bfv8*)&sA[cur][kh][(wr + ((mg) * 4 + j_) * 16 + fr) * 32 + cswz]; \
    __builtin_amdgcn_s_setprio(1);                                                   \
    _Pragma("unroll")                                                                \
    for (int j_ = 0; j_ < 4; j_++)                                                   \
      _Pragma("unroll")                                                              \
      for (int n_ = 0; n_ < 4; n_++)                                                 \
        acc[(mg) * 4 + j_][n_] = mfma16(af_[j_], bf[n_], acc[(mg) * 4 + j_][n_]);    \
    __builtin_amdgcn_s_setprio(0);                                                   \
  }

  int NT = K / 64;
  STAGE256(0, 0, false, 0);
  STAGE256(0, 0, true, 0);
  STAGE256(0, 1, false, 0);
  STAGE256(0, 1, true, 0);

  for (int t = 0; t < NT - 1; t++) {
    int cur = t & 1, nxt = cur ^ 1;
    asm volatile("s_waitcnt vmcnt(4)" ::: "memory");
    __builtin_amdgcn_s_barrier();
    STAGE256(nxt, 0, false, t + 1);
    COMPUTE256(cur, 0, 0, true);
    STAGE256(nxt, 0, true, t + 1);
    COMPUTE256(cur, 0, 1, false);
    asm volatile("s_waitcnt vmcnt(4)" ::: "memory");
    __builtin_amdgcn_s_barrier();
    STAGE256(nxt, 1, false, t + 1);
    COMPUTE256(cur, 1, 0, true);
    STAGE256(nxt, 1, true, t + 1);
    COMPUTE256(cur, 1, 1, false);
  }
  {
    int cur = (NT - 1) & 1;
    asm volatile("s_waitcnt vmcnt(4)" ::: "memory");
    __builtin_amdgcn_s_barrier();
    COMPUTE256(cur, 0, 0, true);
    COMPUTE256(cur, 0, 1, false);
    asm volatile("s_waitcnt vmcnt(0)" ::: "memory");
    __builtin_amdgcn_s_barrier();
    COMPUTE256(cur, 1, 0, true);
    COMPUTE256(cur, 1, 1, false);
  }
#undef STAGE256
#undef COMPUTE256

#pragma unroll
  for (int m = 0; m < 8; m++)
#pragma unroll
    for (int n = 0; n < 4; n++)
#pragma unroll
      for (int j = 0; j < 4; j++) {
        int r = row0 + wr + m * 16 + fq * 4 + j;
        int c = col0 + wc + n * 16 + fr;
        if constexpr (__is_same(OT, float)) {
          Cb[(size_t)r * N + c] = acc[m][n][j];
        } else {
          Cb[(size_t)r * N + c] = __float2bfloat16(acc[m][n][j]);
        }
      }
}

// ---------------- flash attention v5e (r24-best: 64 VGPR, 50K LDS) -----------
//  A: vmcnt(2)+bar  -> K landed; QK^T+softmax while V streams in
//  B: vmcnt(0)+bar  -> V landed & all waves past QK^T; issue K(t+1); PV
//  C: bar           -> all waves past PV; issue V(t+1)
// Deferred denominator + skip-identity rescale + rcp epilogue (all exact-class).
#define PSTR 68
__global__ __launch_bounds__(512) void k_attn5(const __hip_bfloat16* __restrict__ Qb,
                                               const __hip_bfloat16* __restrict__ KVb,
                                               const __hip_bfloat16* __restrict__ VTb,
                                               __hip_bfloat16* __restrict__ ctx) {
  __shared__ short sK[64 * 128];        // [k][d], rows 256B, 16 chunks
  __shared__ short sV[128 * 64];        // [d][k], rows 128B, 8 chunks
  __shared__ short sP[8][16 * PSTR];    // per-wave P[16 q][64 k]

  const int nQB = S_ / 128;             // 16
  int blk = blockIdx.x;
  int qb = (nQB - 1) - (blk % nQB);     // heavy blocks dispatched first
  int bh = blk / nQB;
  int h = bh % H_;
  int b = bh / H_;
  int g = h / GROUP_;
  int q0 = qb * 128;

  int t = threadIdx.x;
  int wid = t >> 6;
  int l = t & 63;
  int fr = l & 15, fq = l >> 4, fo = fq * 8;
  int wq0 = q0 + wid * 16;              // this wave's q rows

  const short* qp = (const short*)Qb + (size_t)b * S_ * H_ * HD_ + (size_t)h * HD_;
  const short* kp = (const short*)KVb + (size_t)b * S_ * KVSTR_ + (size_t)g * HD_;
  const short* vp = (const short*)VTb + (size_t)(b * G_ + g) * HD_ * S_;

  bfv8 qf[4];
#pragma unroll
  for (int c = 0; c < 4; c++)
    qf[c] = *(const bfv8*)(qp + (size_t)(wq0 + fr) * (H_ * HD_) + c * 32 + fo);

  f32x4 acc[8];
#pragma unroll
  for (int n = 0; n < 8; n++) acc[n] = (f32x4){0.f, 0.f, 0.f, 0.f};
  float m[4], ls[4];
#pragma unroll
  for (int j = 0; j < 4; j++) { m[j] = -INFINITY; ls[j] = 0.f; }

  // staging lane decomposition
  int krow_i = l >> 4;   // K: 4 rows per issue
  int kchk = l & 15;     // K chunk 0..15
  int vrow_i = l >> 3;   // V: 8 rows per issue
  int vchk = l & 7;      // V chunk 0..7

#define STAGE_K(k0s)                                                                 \
  _Pragma("unroll")                                                                  \
  for (int j = 0; j < 2; j++) {                                                      \
    int base = wid * 8 + j * 4;                                                      \
    int r = base + krow_i;                                                           \
    gload16(kp + (size_t)((k0s) + r) * KVSTR_ + ((kchk ^ (r & 7)) * 8),              \
            &sK[base * 128]);                                                        \
  }
#define STAGE_V(k0s)                                                                 \
  _Pragma("unroll")                                                                  \
  for (int j = 0; j < 2; j++) {                                                      \
    int base = wid * 16 + j * 8;                                                     \
    int r = base + vrow_i;                                                           \
    gload16(vp + (size_t)r * S_ + (k0s) + ((vchk ^ (r & 7)) * 8), &sV[base * 64]);   \
  }

  int nkt = 2 * qb + 2;  // 64-k tiles covering k <= q0+127
  // prologue: stage tile 0 (K first, then V — vmcnt is oldest-first)
  STAGE_K(0);
  STAGE_V(0);

  for (int kt = 0; kt < nkt; kt++) {
    int k0 = kt * 64;
    // ---- A: K landed (V's 2 loads may still be in flight)
    asm volatile("s_waitcnt vmcnt(2)" ::: "memory");
    __builtin_amdgcn_s_barrier();

    // ---- QK^T over 64 k (4 sub-tiles of 16)
    f32x4 sf[4];
#pragma unroll
    for (int ks = 0; ks < 4; ks++) {
      sf[ks] = (f32x4){0.f, 0.f, 0.f, 0.f};
      int row = ks * 16 + fr;
      int rx = row & 7;
#pragma unroll
      for (int c = 0; c < 4; c++) {
        bfv8 kf = *(const bfv8*)&sK[row * 128 + (((c * 4 + fq) ^ rx) * 8)];
        sf[ks] = mfma16(qf[c], kf, sf[ks]);
      }
    }

    // ---- causal mask + online softmax (rows = fq*4+j, cols = ks*16+fr)
    float p[4][4], red[4];
#pragma unroll
    for (int j = 0; j < 4; j++) {
      int q = wq0 + fq * 4 + j;
#pragma unroll
      for (int ks = 0; ks < 4; ks++)
        if (k0 + ks * 16 + fr > q) sf[ks][j] = -INFINITY;
      red[j] = fmaxf(fmaxf(sf[0][j], sf[1][j]), fmaxf(sf[2][j], sf[3][j]));
    }
#pragma unroll
    for (int off = 1; off < 16; off <<= 1)
#pragma unroll
      for (int j = 0; j < 4; j++)
        red[j] = fmaxf(red[j], __shfl_xor(red[j], off, 64));

    // wave-uniform: does any row's max grow this tile? (if not, sc==1 for all)
    bool grow = !__all((red[0] <= m[0]) & (red[1] <= m[1]) &
                       (red[2] <= m[2]) & (red[3] <= m[3]));
    if (grow) {
#pragma unroll
      for (int j = 0; j < 4; j++) {
        float nm = fmaxf(m[j], red[j]);
        float scj = __expf(m[j] - nm);   // row-uniform across the 16 fr-lanes
        m[j] = nm;
        ls[j] *= scj;
#pragma unroll
        for (int n = 0; n < 8; n++) acc[n][j] *= scj;
      }
    }
#pragma unroll
    for (int j = 0; j < 4; j++) {
#pragma unroll
      for (int ks = 0; ks < 4; ks++) p[ks][j] = __expf(sf[ks][j] - m[j]);
      // deferred denominator: per-lane partial (16-lane reduce after the loop)
      ls[j] += (p[0][j] + p[1][j]) + (p[2][j] + p[3][j]);
#pragma unroll
      for (int ks = 0; ks < 4; ks++)
        sP[wid][(fq * 4 + j) * PSTR + ks * 16 + fr] = f2bf_bits(p[ks][j]);
    }

    // ---- B: V landed; all waves past QK^T (sP writes forced sK reads done)
    asm volatile("s_waitcnt vmcnt(0)" ::: "memory");
    __builtin_amdgcn_s_barrier();
    if (kt + 1 < nkt) STAGE_K(k0 + 64);   // overlaps with PV below

    // ---- PV: O += P[16x64] @ V[64x128]  (own-wave sP; in-wave DS order)
    bfv8 pa0 = *(const bfv8*)&sP[wid][fr * PSTR + fo];
    bfv8 pa1 = *(const bfv8*)&sP[wid][fr * PSTR + 32 + fo];
#pragma unroll
    for (int n = 0; n < 8; n++) {
      int row = n * 16 + fr;
      int rx = row & 7;
      bfv8 vf0 = *(const bfv8*)&sV[row * 64 + ((fq ^ rx) * 8)];
      bfv8 vf1 = *(const bfv8*)&sV[row * 64 + (((4 + fq) ^ rx) * 8)];
      acc[n] = mfma16(pa0, vf0, acc[n]);
      acc[n] = mfma16(pa1, vf1, acc[n]);
    }

    // ---- C: all waves past PV -> safe to overwrite sV; overlaps next QK^T
    if (kt + 1 < nkt) {
      __builtin_amdgcn_s_barrier();
      STAGE_V(k0 + 64);
    }
  }
#undef STAGE_K
#undef STAGE_V

  // final 16-lane reduce of the deferred denominator (once, not per tile)
#pragma unroll
  for (int off = 1; off < 16; off <<= 1)
#pragma unroll
    for (int j = 0; j < 4; j++)
      ls[j] += __shfl_xor(ls[j], off, 64);
  float inv[4];
#pragma unroll
  for (int j = 0; j < 4; j++) inv[j] = 1.0f / ls[j];

#pragma unroll
  for (int n = 0; n < 8; n++)
#pragma unroll
    for (int j = 0; j < 4; j++) {
      int q = wq0 + fq * 4 + j;
      float o = acc[n][j] * inv[j];
      ctx[(size_t)(b * S_ + q) * (H_ * HD_) + h * HD_ + n * 16 + fr] = __float2bfloat16(o);
    }
}

extern "C" void kernel_launch(void* const* d_in, const int* in_sizes, int n_in,
                              void* d_out, int out_size, void* d_ws, size_t ws_size,
                              hipStream_t stream) {
  (void)in_sizes; (void)n_in; (void)out_size; (void)ws_size;
  const float* x    = (const float*)d_in[0];
  const float* Wq   = (const float*)d_in[1];
  const float* Wk   = (const float*)d_in[2];
  const float* Wv   = (const float*)d_in[3];
  const float* Wo   = (const float*)d_in[4];
  const float* cosb = (const float*)d_in[5];
  const float* sinb = (const float*)d_in[6];
  // d_in[7] = mask (fixed causal triu), d_in[8] = start_pos (0) — implemented directly.

  char* ws = (char*)d_ws;
  __hip_bfloat16* xb  = (__hip_bfloat16*)(ws + 0);           // (B,S,D) bf16, later Cx
  __hip_bfloat16* WqT = (__hip_bfloat16*)(ws + 33554432);    // 4096x4096, later WoT
  __hip_bfloat16* WkT = (__hip_bfloat16*)(ws + 67108864);    // 1024x4096 \ contiguous:
  __hip_bfloat16* WvT = (__hip_bfloat16*)(ws + 75497472);    // 1024x4096 / WkvT (2048x4096)
  __hip_bfloat16* Qb  = (__hip_bfloat16*)(ws + 83886080);    // (B,S,H,HD)
  __hip_bfloat16* KVb = (__hip_bfloat16*)(ws + 117440512);   // (B,S,16,HD): K slots 0-7, V slots 8-15
  __hip_bfloat16* VTb = (__hip_bfloat16*)(ws + 134217728);   // (B,G,HD,S)
  __hip_bfloat16* Cx  = xb;                                  // alias

  k_cvt<<<(B_ * S_ * D_ / 4 + 255) / 256, 256, 0, stream>>>(x, (ushort*)xb, B_ * S_ * D_ / 4);
  k_transpose<<<dim3(128, 128), 256, 0, stream>>>(Wq, (ushort*)WqT, 4096, 4096);
  k_transpose<<<dim3(32, 128), 256, 0, stream>>>(Wk, (ushort*)WkT, 4096, 1024);
  k_transpose<<<dim3(32, 128), 256, 0, stream>>>(Wv, (ushort*)WvT, 4096, 1024);

  // projections: Q on the 256^2 counted-vmcnt kernel; K+V merged on 128^2 (N=2048)
  k_gemm256<__hip_bfloat16><<<dim3(16, 16), 512, 0, stream>>>(xb, WqT, Qb, 4096, 4096, 4096);
  k_gemm_bt<__hip_bfloat16><<<dim3(16, 32), 256, 0, stream>>>(xb, WkT, KVb, 4096, 2048, 4096);

  // WqT region is free now — put WoT there
  k_transpose<<<dim3(128, 128), 256, 0, stream>>>(Wo, (ushort*)WqT, 4096, 4096);

  // RoPE: Q (stride 32 heads, launch 32) and K-half of KV (stride 16, launch 8)
  k_rope<<<4096 * 32 / 4, 256, 0, stream>>>(Qb, cosb, sinb, 32, 32, SCALE_);
  k_rope<<<4096 * 8 / 4, 256, 0, stream>>>((__hip_bfloat16*)KVb, cosb, sinb, 16, 8, 1.0f);

  // V-half of KV -> VT
  k_transpose_v<<<dim3(4, 64, 16), dim3(32, 8), 0, stream>>>((const ushort*)KVb, (ushort*)VTb,
                                                             KVSTR_, G_);

  k_attn5<<<B_ * H_ * (S_ / 128), 512, 0, stream>>>(Qb, KVb, VTb, Cx);

  // output projection (f32 into d_out) on the 256^2 kernel
  k_gemm256<float><<<dim3(16, 16), 512, 0, stream>>>(Cx, WqT, (float*)d_out, 4096, 4096, 4096);
}

// Round 27
// 679.648 us; speedup vs baseline: 1.1631x; 1.0050x over previous
//
#include <hip/hip_runtime.h>
#include <hip/hip_bf16.h>
#include <math.h>

// Problem constants
#define B_ 2
#define S_ 2048
#define D_ 4096
#define H_ 32
#define G_ 8
#define HD_ 128
#define GROUP_ 4
#define KVSTR_ (2 * G_ * HD_)   // 2048: head-stride of merged KV buffer (16 slots)
#define SCALE_ 0.08838834764831845f

typedef short bfv8 __attribute__((ext_vector_type(8)));   // 8 bf16 (4 VGPRs)
typedef float f32x4 __attribute__((ext_vector_type(4)));

__device__ __forceinline__ f32x4 mfma16(bfv8 a, bfv8 b, f32x4 c) {
  return __builtin_amdgcn_mfma_f32_16x16x32_bf16(a, b, c, 0, 0, 0);
}

__device__ __forceinline__ ushort f2bf_bits(float f) {
  __hip_bfloat16 h = __float2bfloat16(f);
  return *reinterpret_cast<ushort*>(&h);
}

// async global->LDS, 16B per lane; LDS dest = wave-uniform base + lane*16 (HW);
// global src is per-lane (enables source-side swizzle per rule #21).
__device__ __forceinline__ void gload16(const short* g, short* l) {
  __builtin_amdgcn_global_load_lds(
      (const __attribute__((address_space(1))) void*)g,
      (__attribute__((address_space(3))) void*)l, 16, 0, 0);
}

// ---------------- f32 -> bf16 elementwise convert (x) ----------------
__global__ __launch_bounds__(256) void k_cvt(const float* __restrict__ in,
                                             ushort* __restrict__ out, int n4) {
  int i = blockIdx.x * 256 + threadIdx.x;
  if (i >= n4) return;
  float4 v = *(const float4*)(in + (size_t)i * 4);
  ushort4 o;
  o.x = f2bf_bits(v.x); o.y = f2bf_bits(v.y); o.z = f2bf_bits(v.z); o.w = f2bf_bits(v.w);
  *(ushort4*)(out + (size_t)i * 4) = o;
}

// ---------------- transpose (R x C) f32 -> (C x R) bf16, vectorized ----------
__global__ __launch_bounds__(256) void k_transpose(const float* __restrict__ in,
                                                   ushort* __restrict__ out,
                                                   int R, int C) {
  __shared__ ushort tile[32][36];
  int bc = blockIdx.x * 32;
  int br = blockIdx.y * 32;
  int t = threadIdx.x;
  int rr = t >> 3;            // 0..31
  int c4 = (t & 7) * 4;       // 0,4,..,28
  float4 v = *(const float4*)(in + (size_t)(br + rr) * C + bc + c4);
  tile[rr][c4 + 0] = f2bf_bits(v.x);
  tile[rr][c4 + 1] = f2bf_bits(v.y);
  tile[rr][c4 + 2] = f2bf_bits(v.z);
  tile[rr][c4 + 3] = f2bf_bits(v.w);
  __syncthreads();
  int cc = t >> 3;            // 0..31
  int r4 = (t & 7) * 4;       // 0,4,..,28
  ushort4 o;
  o.x = tile[r4 + 0][cc];
  o.y = tile[r4 + 1][cc];
  o.z = tile[r4 + 2][cc];
  o.w = tile[r4 + 3][cc];
  *(ushort4*)(out + (size_t)(bc + cc) * R + br + r4) = o;
}

// V-half of KV (B,S,16,HD) bf16 -> VT (B,G,HD,S) bf16
__global__ __launch_bounds__(256) void k_transpose_v(const ushort* __restrict__ v,
                                                     ushort* __restrict__ vt,
                                                     int hstride, int hoff) {
  __shared__ ushort tile[32][33];
  int bg = blockIdx.z;
  int b = bg / G_, g = bg % G_;
  int s0 = blockIdx.y * 32;
  int h0 = blockIdx.x * 32;
  int tx = threadIdx.x, ty = threadIdx.y;
  const ushort* src = v + (size_t)b * S_ * hstride + (size_t)(hoff + g) * HD_;
  ushort* dst = vt + (size_t)(b * G_ + g) * HD_ * S_;
  for (int ii = 0; ii < 4; ii++) {
    int i = ty + ii * 8;
    tile[i][tx] = src[(size_t)(s0 + i) * hstride + h0 + tx];
  }
  __syncthreads();
  for (int ii = 0; ii < 4; ii++) {
    int i = ty + ii * 8;
    dst[(size_t)(h0 + i) * S_ + s0 + tx] = tile[tx][i];
  }
}

// ---------------- RoPE (in-place, bf16 t; f32 cos/sin), 4 items/block --------
__global__ __launch_bounds__(256) void k_rope(__hip_bfloat16* __restrict__ t,
                                              const float* __restrict__ cosb,
                                              const float* __restrict__ sinb,
                                              int hstride, int nlaunch, float scale) {
  int item = blockIdx.x * 4 + (threadIdx.x >> 6);
  int head = item % nlaunch;
  int row = item / nlaunch;      // b*S + s
  int s = row & (S_ - 1);
  int l = threadIdx.x & 63;
  size_t base = (size_t)row * hstride * HD_ + (size_t)head * HD_;
  float x1 = __bfloat162float(t[base + l]);
  float x2 = __bfloat162float(t[base + 64 + l]);
  float c1 = cosb[s * HD_ + l];
  float sn1 = sinb[s * HD_ + l];
  float c2 = cosb[s * HD_ + 64 + l];
  float sn2 = sinb[s * HD_ + 64 + l];
  t[base + l] = __float2bfloat16((x1 * c1 - x2 * sn1) * scale);
  t[base + 64 + l] = __float2bfloat16((x2 * c2 + x1 * sn2) * scale);
}

// ---------------- GEMM 128^2 (m97 structure) for merged KV projection --------
template <typename OT>
__global__ __launch_bounds__(256) void k_gemm_bt(const __hip_bfloat16* __restrict__ Ab,
                                                 const __hip_bfloat16* __restrict__ BTb,
                                                 OT* __restrict__ Cb,
                                                 int M, int N, int K) {
  __shared__ short sA[128 * 32];
  __shared__ short sB[128 * 32];
  int t = threadIdx.x;
  int w = t >> 6;
  int l = t & 63;
  int row0 = blockIdx.y * 128;
  int col0 = blockIdx.x * 128;
  int wr = (w >> 1) * 64;
  int wc = (w & 1) * 64;
  int fr = l & 15;
  int fq = l >> 4;
  int fo = fq * 8;
  int srow = l >> 2;
  int schk = (l & 3) * 8;

  const short* gA = (const short*)Ab;
  const short* gB = (const short*)BTb;

  f32x4 acc[4][4];
#pragma unroll
  for (int m = 0; m < 4; m++)
#pragma unroll
    for (int n = 0; n < 4; n++) acc[m][n] = (f32x4){0.f, 0.f, 0.f, 0.f};

  for (int k0 = 0; k0 < K; k0 += 32) {
    __syncthreads();
#pragma unroll
    for (int j = 0; j < 2; j++) {
      int r = w * 32 + j * 16;
      gload16(gA + (size_t)(row0 + r + srow) * K + k0 + schk, &sA[r * 32]);
      gload16(gB + (size_t)(col0 + r + srow) * K + k0 + schk, &sB[r * 32]);
    }
    __syncthreads();
    bfv8 af[4], bff[4];
#pragma unroll
    for (int m = 0; m < 4; m++) af[m] = *(const bfv8*)(sA + (wr + m * 16 + fr) * 32 + fo);
#pragma unroll
    for (int n = 0; n < 4; n++) bff[n] = *(const bfv8*)(sB + (wc + n * 16 + fr) * 32 + fo);
#pragma unroll
    for (int m = 0; m < 4; m++)
#pragma unroll
      for (int n = 0; n < 4; n++)
        acc[m][n] = mfma16(af[m], bff[n], acc[m][n]);
  }
#pragma unroll
  for (int m = 0; m < 4; m++)
#pragma unroll
    for (int n = 0; n < 4; n++)
#pragma unroll
      for (int j = 0; j < 4; j++) {
        int r = row0 + wr + m * 16 + fq * 4 + j;
        int c = col0 + wc + n * 16 + fr;
        if constexpr (__is_same(OT, float)) {
          Cb[(size_t)r * N + c] = acc[m][n][j];
        } else {
          Cb[(size_t)r * N + c] = __float2bfloat16(acc[m][n][j]);
        }
      }
}

// ---------------- GEMM 256^2, BK=64, 8 waves, 4-phase counted-vmcnt ----------
// (r22-best configuration: dim3(16,16) grid, setprio around MFMA clusters)
template <typename OT>
__global__ __launch_bounds__(512, 2) void k_gemm256(const __hip_bfloat16* __restrict__ Ab,
                                                    const __hip_bfloat16* __restrict__ BTb,
                                                    OT* __restrict__ Cb,
                                                    int M, int N, int K) {
  __shared__ short sA[2][2][8192];
  __shared__ short sB[2][2][8192];
  int tid = threadIdx.x;
  int wid = tid >> 6;
  int l = tid & 63;
  int wr = (wid >> 2) * 128;
  int wc = (wid & 3) * 64;
  int fr = l & 15, fq = l >> 4;
  int cswz = (fq ^ ((fr >> 1) & 3)) * 8;
  int row0 = blockIdx.y * 256, col0 = blockIdx.x * 256;
  int sr = l >> 2;
  int schunk = ((l & 3) ^ (((wid * 16 + sr) >> 1) & 3)) * 8;
  const short* gA = (const short*)Ab;
  const short* gB = (const short*)BTb;

  f32x4 acc[8][4];
#pragma unroll
  for (int m = 0; m < 8; m++)
#pragma unroll
    for (int n = 0; n < 4; n++) acc[m][n] = (f32x4){0.f, 0.f, 0.f, 0.f};

#define STAGE256(buf, kh, isB, kt)                                                   \
  {                                                                                  \
    const short* g_ = (isB) ? gB : gA;                                               \
    int b0_ = (isB) ? col0 : row0;                                                   \
    short* s_ = (isB) ? &sB[buf][kh][0] : &sA[buf][kh][0];                           \
    int k0_ = (kt) * 64 + (kh) * 32;                                                 \
    _Pragma("unroll")                                                                \
    for (int i_ = 0; i_ < 2; i_++) {                                                 \
      int r_ = i_ * 128 + wid * 16 + sr;                                             \
      gload16(g_ + (size_t)(b0_ + r_) * K + k0_ + schunk,                            \
              s_ + (i_ * 128 + wid * 16) * 32);                                      \
    }                                                                                \
  }

  bfv8 bf[4];
#define COMPUTE256(cur, kh, mg, loadB)                                               \
  {                                                                                  \
    if (loadB) {                                                                     \
      _Pragma("unroll")                                                              \
      for (int n_ = 0; n_ < 4; n_++)                                                 \
        bf[n_] = *(const bfv8*)&sB[cur][kh][(wc + n_ * 16 + fr) * 32 + cswz];        \
    }                                                                                \
    bfv8 af_[4];                                                                     \
    _Pragma("unroll")                                                                \
    for (int j_ = 0; j_ < 4; j_++)                                                   \
      af_[j_] = *(const bfv8*)&sA[cur][kh][(wr + ((mg) * 4 + j_) * 16 + fr) * 32 + cswz]; \
    __builtin_amdgcn_s_setprio(1);                                                   \
    _Pragma("unroll")                                                                \
    for (int j_ = 0; j_ < 4; j_++)                                                   \
      _Pragma("unroll")                                                              \
      for (int n_ = 0; n_ < 4; n_++)                                                 \
        acc[(mg) * 4 + j_][n_] = mfma16(af_[j_], bf[n_], acc[(mg) * 4 + j_][n_]);    \
    __builtin_amdgcn_s_setprio(0);                                                   \
  }

  int NT = K / 64;
  STAGE256(0, 0, false, 0);
  STAGE256(0, 0, true, 0);
  STAGE256(0, 1, false, 0);
  STAGE256(0, 1, true, 0);

  for (int t = 0; t < NT - 1; t++) {
    int cur = t & 1, nxt = cur ^ 1;
    asm volatile("s_waitcnt vmcnt(4)" ::: "memory");
    __builtin_amdgcn_s_barrier();
    STAGE256(nxt, 0, false, t + 1);
    COMPUTE256(cur, 0, 0, true);
    STAGE256(nxt, 0, true, t + 1);
    COMPUTE256(cur, 0, 1, false);
    asm volatile("s_waitcnt vmcnt(4)" ::: "memory");
    __builtin_amdgcn_s_barrier();
    STAGE256(nxt, 1, false, t + 1);
    COMPUTE256(cur, 1, 0, true);
    STAGE256(nxt, 1, true, t + 1);
    COMPUTE256(cur, 1, 1, false);
  }
  {
    int cur = (NT - 1) & 1;
    asm volatile("s_waitcnt vmcnt(4)" ::: "memory");
    __builtin_amdgcn_s_barrier();
    COMPUTE256(cur, 0, 0, true);
    COMPUTE256(cur, 0, 1, false);
    asm volatile("s_waitcnt vmcnt(0)" ::: "memory");
    __builtin_amdgcn_s_barrier();
    COMPUTE256(cur, 1, 0, true);
    COMPUTE256(cur, 1, 1, false);
  }
#undef STAGE256
#undef COMPUTE256

#pragma unroll
  for (int m = 0; m < 8; m++)
#pragma unroll
    for (int n = 0; n < 4; n++)
#pragma unroll
      for (int j = 0; j < 4; j++) {
        int r = row0 + wr + m * 16 + fq * 4 + j;
        int c = col0 + wc + n * 16 + fr;
        if constexpr (__is_same(OT, float)) {
          Cb[(size_t)r * N + c] = acc[m][n][j];
        } else {
          Cb[(size_t)r * N + c] = __float2bfloat16(acc[m][n][j]);
        }
      }
}

// ---------------- flash attention v5e (session-best: 64 VGPR, 50K LDS) -------
//  A: vmcnt(2)+bar  -> K landed; QK^T+softmax while V streams in
//  B: vmcnt(0)+bar  -> V landed & all waves past QK^T; issue K(t+1); PV
//  C: bar           -> all waves past PV; issue V(t+1)
// Deferred denominator + skip-identity rescale + rcp epilogue (all exact-class).
#define PSTR 68
__global__ __launch_bounds__(512) void k_attn5(const __hip_bfloat16* __restrict__ Qb,
                                               const __hip_bfloat16* __restrict__ KVb,
                                               const __hip_bfloat16* __restrict__ VTb,
                                               __hip_bfloat16* __restrict__ ctx) {
  __shared__ short sK[64 * 128];        // [k][d], rows 256B, 16 chunks
  __shared__ short sV[128 * 64];        // [d][k], rows 128B, 8 chunks
  __shared__ short sP[8][16 * PSTR];    // per-wave P[16 q][64 k]

  const int nQB = S_ / 128;             // 16
  int blk = blockIdx.x;
  int qb = (nQB - 1) - (blk % nQB);     // heavy blocks dispatched first
  int bh = blk / nQB;
  int h = bh % H_;
  int b = bh / H_;
  int g = h / GROUP_;
  int q0 = qb * 128;

  int t = threadIdx.x;
  int wid = t >> 6;
  int l = t & 63;
  int fr = l & 15, fq = l >> 4, fo = fq * 8;
  int wq0 = q0 + wid * 16;              // this wave's q rows

  const short* qp = (const short*)Qb + (size_t)b * S_ * H_ * HD_ + (size_t)h * HD_;
  const short* kp = (const short*)KVb + (size_t)b * S_ * KVSTR_ + (size_t)g * HD_;
  const short* vp = (const short*)VTb + (size_t)(b * G_ + g) * HD_ * S_;

  bfv8 qf[4];
#pragma unroll
  for (int c = 0; c < 4; c++)
    qf[c] = *(const bfv8*)(qp + (size_t)(wq0 + fr) * (H_ * HD_) + c * 32 + fo);

  f32x4 acc[8];
#pragma unroll
  for (int n = 0; n < 8; n++) acc[n] = (f32x4){0.f, 0.f, 0.f, 0.f};
  float m[4], ls[4];
#pragma unroll
  for (int j = 0; j < 4; j++) { m[j] = -INFINITY; ls[j] = 0.f; }

  // staging lane decomposition
  int krow_i = l >> 4;   // K: 4 rows per issue
  int kchk = l & 15;     // K chunk 0..15
  int vrow_i = l >> 3;   // V: 8 rows per issue
  int vchk = l & 7;      // V chunk 0..7

#define STAGE_K(k0s)                                                                 \
  _Pragma("unroll")                                                                  \
  for (int j = 0; j < 2; j++) {                                                      \
    int base = wid * 8 + j * 4;                                                      \
    int r = base + krow_i;                                                           \
    gload16(kp + (size_t)((k0s) + r) * KVSTR_ + ((kchk ^ (r & 7)) * 8),              \
            &sK[base * 128]);                                                        \
  }
#define STAGE_V(k0s)                                                                 \
  _Pragma("unroll")                                                                  \
  for (int j = 0; j < 2; j++) {                                                      \
    int base = wid * 16 + j * 8;                                                     \
    int r = base + vrow_i;                                                           \
    gload16(vp + (size_t)r * S_ + (k0s) + ((vchk ^ (r & 7)) * 8), &sV[base * 64]);   \
  }

  int nkt = 2 * qb + 2;  // 64-k tiles covering k <= q0+127
  // prologue: stage tile 0 (K first, then V — vmcnt is oldest-first)
  STAGE_K(0);
  STAGE_V(0);

  for (int kt = 0; kt < nkt; kt++) {
    int k0 = kt * 64;
    // ---- A: K landed (V's 2 loads may still be in flight)
    asm volatile("s_waitcnt vmcnt(2)" ::: "memory");
    __builtin_amdgcn_s_barrier();

    // ---- QK^T over 64 k (4 sub-tiles of 16)
    f32x4 sf[4];
#pragma unroll
    for (int ks = 0; ks < 4; ks++) {
      sf[ks] = (f32x4){0.f, 0.f, 0.f, 0.f};
      int row = ks * 16 + fr;
      int rx = row & 7;
#pragma unroll
      for (int c = 0; c < 4; c++) {
        bfv8 kf = *(const bfv8*)&sK[row * 128 + (((c * 4 + fq) ^ rx) * 8)];
        sf[ks] = mfma16(qf[c], kf, sf[ks]);
      }
    }

    // ---- causal mask + online softmax (rows = fq*4+j, cols = ks*16+fr)
    float p[4][4], red[4];
#pragma unroll
    for (int j = 0; j < 4; j++) {
      int q = wq0 + fq * 4 + j;
#pragma unroll
      for (int ks = 0; ks < 4; ks++)
        if (k0 + ks * 16 + fr > q) sf[ks][j] = -INFINITY;
      red[j] = fmaxf(fmaxf(sf[0][j], sf[1][j]), fmaxf(sf[2][j], sf[3][j]));
    }
#pragma unroll
    for (int off = 1; off < 16; off <<= 1)
#pragma unroll
      for (int j = 0; j < 4; j++)
        red[j] = fmaxf(red[j], __shfl_xor(red[j], off, 64));

    // wave-uniform: does any row's max grow this tile? (if not, sc==1 for all)
    bool grow = !__all((red[0] <= m[0]) & (red[1] <= m[1]) &
                       (red[2] <= m[2]) & (red[3] <= m[3]));
    if (grow) {
#pragma unroll
      for (int j = 0; j < 4; j++) {
        float nm = fmaxf(m[j], red[j]);
        float scj = __expf(m[j] - nm);   // row-uniform across the 16 fr-lanes
        m[j] = nm;
        ls[j] *= scj;
#pragma unroll
        for (int n = 0; n < 8; n++) acc[n][j] *= scj;
      }
    }
#pragma unroll
    for (int j = 0; j < 4; j++) {
#pragma unroll
      for (int ks = 0; ks < 4; ks++) p[ks][j] = __expf(sf[ks][j] - m[j]);
      // deferred denominator: per-lane partial (16-lane reduce after the loop)
      ls[j] += (p[0][j] + p[1][j]) + (p[2][j] + p[3][j]);
#pragma unroll
      for (int ks = 0; ks < 4; ks++)
        sP[wid][(fq * 4 + j) * PSTR + ks * 16 + fr] = f2bf_bits(p[ks][j]);
    }

    // ---- B: V landed; all waves past QK^T (sP writes forced sK reads done)
    asm volatile("s_waitcnt vmcnt(0)" ::: "memory");
    __builtin_amdgcn_s_barrier();
    if (kt + 1 < nkt) STAGE_K(k0 + 64);   // overlaps with PV below

    // ---- PV: O += P[16x64] @ V[64x128]  (own-wave sP; in-wave DS order)
    bfv8 pa0 = *(const bfv8*)&sP[wid][fr * PSTR + fo];
    bfv8 pa1 = *(const bfv8*)&sP[wid][fr * PSTR + 32 + fo];
#pragma unroll
    for (int n = 0; n < 8; n++) {
      int row = n * 16 + fr;
      int rx = row & 7;
      bfv8 vf0 = *(const bfv8*)&sV[row * 64 + ((fq ^ rx) * 8)];
      bfv8 vf1 = *(const bfv8*)&sV[row * 64 + (((4 + fq) ^ rx) * 8)];
      acc[n] = mfma16(pa0, vf0, acc[n]);
      acc[n] = mfma16(pa1, vf1, acc[n]);
    }

    // ---- C: all waves past PV -> safe to overwrite sV; overlaps next QK^T
    if (kt + 1 < nkt) {
      __builtin_amdgcn_s_barrier();
      STAGE_V(k0 + 64);
    }
  }
#undef STAGE_K
#undef STAGE_V

  // final 16-lane reduce of the deferred denominator (once, not per tile)
#pragma unroll
  for (int off = 1; off < 16; off <<= 1)
#pragma unroll
    for (int j = 0; j < 4; j++)
      ls[j] += __shfl_xor(ls[j], off, 64);
  float inv[4];
#pragma unroll
  for (int j = 0; j < 4; j++) inv[j] = 1.0f / ls[j];

#pragma unroll
  for (int n = 0; n < 8; n++)
#pragma unroll
    for (int j = 0; j < 4; j++) {
      int q = wq0 + fq * 4 + j;
      float o = acc[n][j] * inv[j];
      ctx[(size_t)(b * S_ + q) * (H_ * HD_) + h * HD_ + n * 16 + fr] = __float2bfloat16(o);
    }
}

extern "C" void kernel_launch(void* const* d_in, const int* in_sizes, int n_in,
                              void* d_out, int out_size, void* d_ws, size_t ws_size,
                              hipStream_t stream) {
  (void)in_sizes; (void)n_in; (void)out_size; (void)ws_size;
  const float* x    = (const float*)d_in[0];
  const float* Wq   = (const float*)d_in[1];
  const float* Wk   = (const float*)d_in[2];
  const float* Wv   = (const float*)d_in[3];
  const float* Wo   = (const float*)d_in[4];
  const float* cosb = (const float*)d_in[5];
  const float* sinb = (const float*)d_in[6];
  // d_in[7] = mask (fixed causal triu), d_in[8] = start_pos (0) — implemented directly.

  char* ws = (char*)d_ws;
  __hip_bfloat16* xb  = (__hip_bfloat16*)(ws + 0);           // (B,S,D) bf16, later Cx
  __hip_bfloat16* WqT = (__hip_bfloat16*)(ws + 33554432);    // 4096x4096, later WoT
  __hip_bfloat16* WkT = (__hip_bfloat16*)(ws + 67108864);    // 1024x4096 \ contiguous:
  __hip_bfloat16* WvT = (__hip_bfloat16*)(ws + 75497472);    // 1024x4096 / WkvT (2048x4096)
  __hip_bfloat16* Qb  = (__hip_bfloat16*)(ws + 83886080);    // (B,S,H,HD)
  __hip_bfloat16* KVb = (__hip_bfloat16*)(ws + 117440512);   // (B,S,16,HD): K slots 0-7, V slots 8-15
  __hip_bfloat16* VTb = (__hip_bfloat16*)(ws + 134217728);   // (B,G,HD,S)
  __hip_bfloat16* Cx  = xb;                                  // alias

  k_cvt<<<(B_ * S_ * D_ / 4 + 255) / 256, 256, 0, stream>>>(x, (ushort*)xb, B_ * S_ * D_ / 4);
  k_transpose<<<dim3(128, 128), 256, 0, stream>>>(Wq, (ushort*)WqT, 4096, 4096);
  k_transpose<<<dim3(32, 128), 256, 0, stream>>>(Wk, (ushort*)WkT, 4096, 1024);
  k_transpose<<<dim3(32, 128), 256, 0, stream>>>(Wv, (ushort*)WvT, 4096, 1024);

  // projections: Q on the 256^2 counted-vmcnt kernel; K+V merged on 128^2 (N=2048)
  k_gemm256<__hip_bfloat16><<<dim3(16, 16), 512, 0, stream>>>(xb, WqT, Qb, 4096, 4096, 4096);
  k_gemm_bt<__hip_bfloat16><<<dim3(16, 32), 256, 0, stream>>>(xb, WkT, KVb, 4096, 2048, 4096);

  // WqT region is free now — put WoT there
  k_transpose<<<dim3(128, 128), 256, 0, stream>>>(Wo, (ushort*)WqT, 4096, 4096);

  // RoPE: Q (stride 32 heads, launch 32) and K-half of KV (stride 16, launch 8)
  k_rope<<<4096 * 32 / 4, 256, 0, stream>>>(Qb, cosb, sinb, 32, 32, SCALE_);
  k_rope<<<4096 * 8 / 4, 256, 0, stream>>>((__hip_bfloat16*)KVb, cosb, sinb, 16, 8, 1.0f);

  // V-half of KV -> VT
  k_transpose_v<<<dim3(4, 64, 16), dim3(32, 8), 0, stream>>>((const ushort*)KVb, (ushort*)VTb,
                                                             KVSTR_, G_);

  k_attn5<<<B_ * H_ * (S_ / 128), 512, 0, stream>>>(Qb, KVb, VTb, Cx);

  // output projection (f32 into d_out) on the 256^2 kernel
  k_gemm256<float><<<dim3(16, 16), 512, 0, stream>>>(Cx, WqT, (float*)d_out, 4096, 4096, 4096);
}